// Round 9
// baseline (48.892 us; speedup 1.0000x reference)
//
#include <hip/hip_runtime.h>
#include <hip/hip_bf16.h>
#include <stdint.h>

// x [8,2048,768] f32, prototypes [1024,768] f32
// out = distances [16384,1024] f32 ++ prototypes copy [1024,768] f32
#define M_ROWS 16384
#define N_COLS 1024
#define K_DIM  768
#define NIT    6    // main-loop iterations; each covers 2 K-tiles of BK=64

typedef __attribute__((ext_vector_type(8))) short bf16x8;
typedef __attribute__((ext_vector_type(4))) float f32x4;

__device__ __forceinline__ void async_copy16(void* lds, const void* g) {
  __builtin_amdgcn_global_load_lds(
      (const __attribute__((address_space(1))) unsigned int*)g,
      (__attribute__((address_space(3))) unsigned int*)lds,
      16, 0, 0);
}

__device__ __forceinline__ unsigned short f2bf(float f) {
  __hip_bfloat16 h = __float2bfloat16(f);
  return *reinterpret_cast<unsigned short*>(&h);
}

// Combined prep, one launch: blocks [0,4096) process x rows (4/block);
// blocks [4096,4352) process prototype rows (4/block) incl. f32 passthrough.
__global__ void prep_all(const float* __restrict__ x,
                         const float* __restrict__ p,
                         unsigned short* __restrict__ xb,
                         unsigned short* __restrict__ pbu,
                         float* __restrict__ xsq,
                         float* __restrict__ psq,
                         float* __restrict__ proto_out) {
  const int b = blockIdx.x;
  const int wid = threadIdx.x >> 6;
  const int lane = threadIdx.x & 63;
  const float* src;
  unsigned short* dst;
  float* sq;
  float* cp;
  int row;
  if (b < M_ROWS / 4) {
    row = b * 4 + wid;
    src = x; dst = xb; sq = xsq; cp = nullptr;
  } else {
    row = (b - M_ROWS / 4) * 4 + wid;
    src = p; dst = pbu; sq = psq; cp = proto_out;
  }
  const float4* r = (const float4*)(src + (size_t)row * K_DIM);
  ushort4* rb = (ushort4*)(dst + (size_t)row * K_DIM);
  float4* cpv = cp ? (float4*)(cp + (size_t)row * K_DIM) : nullptr;
  float acc = 0.f;
#pragma unroll
  for (int i = 0; i < 3; ++i) {
    float4 v = r[i * 64 + lane];
    acc += v.x * v.x + v.y * v.y + v.z * v.z + v.w * v.w;
    ushort4 u;
    u.x = f2bf(v.x); u.y = f2bf(v.y); u.z = f2bf(v.z); u.w = f2bf(v.w);
    rb[i * 64 + lane] = u;
    if (cpv) cpv[i * 64 + lane] = v;
  }
#pragma unroll
  for (int off = 32; off; off >>= 1) acc += __shfl_down(acc, off);
  if (lane == 0) sq[row] = acc;
}

// ---------------------------------------------------------------------------
// 8-phase 256x256 GEMM (m201-style template, derived for K=768 / 12 K-tiles).
// 512 thr = 8 waves (2M x 4N), per-wave out 128x64. BK=64; 2 K-tiles/iter.
// LDS 128 KB: [buf][op A=0/B=1][half][128 rows x 64 bf16 = 16 KB].
// Swizzle (R5-proven, 0 conflicts): stored slot = slot ^ (row & 7); source
// pre-swizzled for the linear global_load_lds dest (rule #21).
// Per phase: {ds_read subtile || 1 half-tile prefetch} -> barrier ->
// lgkmcnt(0) -> setprio(1)+16 MFMA -> barrier.  vmcnt(4) ONLY at p3/p7
// (2 half-tiles = 4 loads stay in flight across barriers; never drain to 0).
// WAR-safety: each prefetch targets a region whose last ds_read retired
// before the previous phase's end-barrier.
// ---------------------------------------------------------------------------
__global__ __launch_bounds__(512, 2) void dist_gemm(
    const __hip_bfloat16* __restrict__ xb,
    const __hip_bfloat16* __restrict__ pb,
    const float* __restrict__ xsq,
    const float* __restrict__ psq,
    float* __restrict__ out) {
  __shared__ char L[131072];  // [buf]*65536 + [op]*32768 + [half]*16384

  const int flat = blockIdx.x;       // 256 blocks = 64 bm x 4 bn
  const int xcd = flat & 7;
  const int local = flat >> 3;       // 0..31
  const int bm = xcd * 8 + (local >> 2);   // 0..63
  const int bn = local & 3;                // 0..3

  const int tid = threadIdx.x;
  const int wave = tid >> 6;
  const int lane = tid & 63;
  const int wm = wave >> 2;   // 0..1 -> A half
  const int wn = wave & 3;    // 0..3
  const int rl = lane & 15;
  const int kq = lane >> 4;   // 0..3

  f32x4 acc[8][4] = {};
  bf16x8 af[4][2];   // current mi-half fragments
  bf16x8 bfr[4][2];  // all 4 ni fragments (both halves held)

  const __hip_bfloat16* Abase = xb + (size_t)(bm * 256) * K_DIM;
  const __hip_bfloat16* Bbase = pb + (size_t)(bn * 256) * K_DIM;

  const int rih = tid >> 3;                     // 0..63
  const int g8 = ((tid & 7) ^ (rih & 7)) * 8;   // pre-swizzled source offset

  // stage one 128x64 half-tile (2 x global_load_lds per thread)
#define STG(buf_, op_, h_, base_, kt_)                                       \
  do {                                                                       \
    _Pragma("unroll") for (int c = 0; c < 2; ++c)                            \
        async_copy16(L + (buf_) * 65536 + (op_) * 32768 + (h_) * 16384 +     \
                         (c * 512 + tid) * 16,                               \
                     (base_) + (size_t)((h_) * 128 + c * 64 + rih) * K_DIM + \
                         (kt_) * 64 + g8);                                   \
  } while (0)

  // A fragments for mi-half mh_: rows (in wave's half wm) mh_*64+mi2*16+rl
#define RD_A(buf_, mh_)                                                      \
  do {                                                                       \
    _Pragma("unroll") for (int mi2 = 0; mi2 < 4; ++mi2)                      \
        _Pragma("unroll") for (int kk = 0; kk < 2; ++kk) {                   \
      const int r_ = (mh_) * 64 + mi2 * 16 + rl;                             \
      af[mi2][kk] = *(const bf16x8*)(L + (buf_) * 65536 + wm * 16384 +       \
                                     r_ * 128 +                              \
                                     (((kk * 4 + kq) ^ (r_ & 7)) << 4));     \
    }                                                                        \
  } while (0)

  // B fragments for ni-half nh_: B-tile row wn*64+ni*16+rl -> half wn>>1
#define RD_B(buf_, nh_)                                                      \
  do {                                                                       \
    _Pragma("unroll") for (int ni2 = 0; ni2 < 2; ++ni2)                      \
        _Pragma("unroll") for (int kk = 0; kk < 2; ++kk) {                   \
      const int r_ = (wn & 1) * 64 + ((nh_) * 2 + ni2) * 16 + rl;            \
      bfr[(nh_) * 2 + ni2][kk] =                                             \
          *(const bf16x8*)(L + (buf_) * 65536 + 32768 + (wn >> 1) * 16384 +  \
                           r_ * 128 + (((kk * 4 + kq) ^ (r_ & 7)) << 4));    \
    }                                                                        \
  } while (0)

#define MMA(mh_, nh_)                                                        \
  do {                                                                       \
    __builtin_amdgcn_s_setprio(1);                                           \
    _Pragma("unroll") for (int mi2 = 0; mi2 < 4; ++mi2)                      \
        _Pragma("unroll") for (int ni2 = 0; ni2 < 2; ++ni2)                  \
            _Pragma("unroll") for (int kk = 0; kk < 2; ++kk)                 \
        acc[(mh_) * 4 + mi2][(nh_) * 2 + ni2] =                              \
            __builtin_amdgcn_mfma_f32_16x16x32_bf16(                         \
                af[mi2][kk], bfr[(nh_) * 2 + ni2][kk],                       \
                acc[(mh_) * 4 + mi2][(nh_) * 2 + ni2], 0, 0, 0);             \
    __builtin_amdgcn_s_setprio(0);                                           \
  } while (0)

#define BAR()   asm volatile("s_barrier" ::: "memory")
#define LGKM0() asm volatile("s_waitcnt lgkmcnt(0)" ::: "memory")

  // prologue: tile 0 (A+B -> buf0), tile 1 B -> buf1 (A of tile 1 is staged
  // by p0/p1 of iteration 0, matching the steady-state pattern).
  STG(0, 0, 0, Abase, 0);
  STG(0, 0, 1, Abase, 0);
  STG(0, 1, 0, Bbase, 0);
  STG(0, 1, 1, Bbase, 0);
  STG(1, 1, 0, Bbase, 1);
  STG(1, 1, 1, Bbase, 1);
  asm volatile("s_waitcnt vmcnt(4)" ::: "memory");  // tile 0 landed; B1 in flight
  BAR();

  for (int i = 0; i < NIT; ++i) {
    const int T1 = 2 * i + 1;
    const int T2n = 2 * i + 2;
    const int T3n = 2 * i + 3;
    const bool pf = (i < NIT - 1);

    // ---- p0: Q(miL,niL) on buf0; stage A(T1)h0 -> buf1 ----
    RD_A(0, 0); RD_B(0, 0);
    STG(1, 0, 0, Abase, T1);
    BAR(); LGKM0();
    MMA(0, 0);
    BAR();
    // ---- p1: Q(miL,niH); stage A(T1)h1 ----
    RD_B(0, 1);
    STG(1, 0, 1, Abase, T1);
    BAR(); LGKM0();
    MMA(0, 1);
    BAR();
    // ---- p2: Q(miH,niL); stage B(T2n)h0 -> buf0 (B reads done by end-p1) --
    RD_A(0, 1);
    if (pf) STG(0, 1, 0, Bbase, T2n);
    BAR(); LGKM0();
    MMA(1, 0);
    BAR();
    // ---- p3: Q(miH,niH); stage B(T2n)h1; boundary wait for tile T1 ----
    if (pf) STG(0, 1, 1, Bbase, T2n);
    BAR();
    MMA(1, 1);
    if (pf) asm volatile("s_waitcnt vmcnt(4)" ::: "memory");
    else    asm volatile("s_waitcnt vmcnt(0)" ::: "memory");
    BAR();

    // ---- p4: Q(miL,niL) on buf1 (tile T1); stage A(T2n)h0 -> buf0 ----
    RD_A(1, 0); RD_B(1, 0);
    if (pf) STG(0, 0, 0, Abase, T2n);
    BAR(); LGKM0();
    MMA(0, 0);
    BAR();
    // ---- p5: Q(miL,niH); stage A(T2n)h1 ----
    RD_B(1, 1);
    if (pf) STG(0, 0, 1, Abase, T2n);
    BAR(); LGKM0();
    MMA(0, 1);
    BAR();
    // ---- p6: Q(miH,niL); stage B(T3n)h0 -> buf1 ----
    RD_A(1, 1);
    if (pf) STG(1, 1, 0, Bbase, T3n);
    BAR(); LGKM0();
    MMA(1, 0);
    BAR();
    // ---- p7: Q(miH,niH); stage B(T3n)h1; boundary wait for tile T0+2 ----
    if (pf) STG(1, 1, 1, Bbase, T3n);
    BAR();
    MMA(1, 1);
    if (pf) asm volatile("s_waitcnt vmcnt(4)" ::: "memory");
    BAR();
  }
#undef STG
#undef RD_A
#undef RD_B
#undef MMA
#undef BAR
#undef LGKM0

  // epilogue: dist = xsq[row] + psq[col] - 2*acc
  // C/D layout: col = lane&15, row = (lane>>4)*4 + reg
  const int c0 = bn * 256 + wn * 64;
  const int r0 = bm * 256 + wm * 128;
#pragma unroll
  for (int mf = 0; mf < 8; ++mf) {
#pragma unroll
    for (int nf = 0; nf < 4; ++nf) {
      const int col = c0 + nf * 16 + rl;
      const float ps = psq[col];
#pragma unroll
      for (int r = 0; r < 4; ++r) {
        const int row = r0 + mf * 16 + kq * 4 + r;
        out[(size_t)row * N_COLS + col] = xsq[row] + ps - 2.0f * acc[mf][nf][r];
      }
    }
  }
}

extern "C" void kernel_launch(void* const* d_in, const int* in_sizes, int n_in,
                              void* d_out, int out_size, void* d_ws, size_t ws_size,
                              hipStream_t stream) {
  const float* x = (const float*)d_in[0];
  const float* p = (const float*)d_in[1];
  float* out = (float*)d_out;
  char* ws = (char*)d_ws;

  float* xsq = (float*)ws;                                   // 64 KB
  float* psq = (float*)(ws + 65536);                         // 4 KB
  unsigned short* xb = (unsigned short*)(ws + 69632);        // 24 MB
  unsigned short* pbu = xb + (size_t)M_ROWS * K_DIM;         // 1.5 MB
  float* proto_out = out + (size_t)M_ROWS * N_COLS;

  prep_all<<<M_ROWS / 4 + N_COLS / 4, 256, 0, stream>>>(x, p, xb, pbu, xsq,
                                                        psq, proto_out);

  dist_gemm<<<256, 512, 0, stream>>>((const __hip_bfloat16*)xb,
                                     (const __hip_bfloat16*)pbu,
                                     xsq, psq, out);
}